// Round 10
// baseline (72.161 us; speedup 1.0000x reference)
//
#include <hip/hip_runtime.h>

constexpr int N_TOKENS    = 65536;
constexpr int N_FEATURES  = 8;
constexpr int VOCAB       = 1026;
constexpr int EMB_DIM     = 256;
constexpr int N_ROWS      = N_FEATURES * VOCAB;          // 8208
constexpr int TABLE_ELEMS = N_ROWS * EMB_DIM;            // 2,101,248

constexpr size_t SCALE_OFF = (size_t)TABLE_ELEMS;
constexpr size_t WS_NEED   = SCALE_OFF + (size_t)N_ROWS * sizeof(float);

using v4f = __attribute__((ext_vector_type(4))) float;
using v4i = __attribute__((ext_vector_type(4))) int;

// ---------- prep: fp32 table -> per-row symmetric int8 (unchanged) ----------
__global__ __launch_bounds__(256) void quant_table_i8(
    const float* __restrict__ src,
    signed char* __restrict__ qtab,
    float*       __restrict__ scales)
{
    const int wid  = (blockIdx.x * 256 + threadIdx.x) >> 6;   // row
    const int lane = threadIdx.x & 63;

    const v4f v = __builtin_nontemporal_load(
        reinterpret_cast<const v4f*>(src + (size_t)wid * EMB_DIM) + lane);

    float m = fmaxf(fmaxf(fabsf(v.x), fabsf(v.y)), fmaxf(fabsf(v.z), fabsf(v.w)));
#pragma unroll
    for (int off = 32; off >= 1; off >>= 1)
        m = fmaxf(m, __shfl_xor(m, off));

    const float r = (m > 0.f) ? (127.0f / m) : 0.f;
    const int qx = (int)rintf(v.x * r);
    const int qy = (int)rintf(v.y * r);
    const int qz = (int)rintf(v.z * r);
    const int qw = (int)rintf(v.w * r);
    const unsigned int packed = (qx & 255) | ((qy & 255) << 8) |
                                ((qz & 255) << 16) | ((unsigned)(qw & 255) << 24);
    *reinterpret_cast<unsigned int*>(qtab + (size_t)wid * EMB_DIM + lane * 4) = packed;

    if (lane == 0) scales[wid] = m * (1.0f / 127.0f);
}

// ---------- main: L2-protected gather-sum ----------
// 32 lanes/token, 8 tokens/block, 1 token/thread-column. Two levers vs R9:
// (1) output stores use sc0|sc1|nt full-cache-bypass so the 64 MiB write
//     stream cannot evict the 2.1 MB int8 table from per-XCD L2;
// (2) lean VGPR + __launch_bounds__(256,8) -> 32 waves/CU (was ~20) for
//     more outstanding gather concurrency.
__global__ __launch_bounds__(256, 8) void emb_gather_sum_i8hc(
    const int*         __restrict__ indices,  // [N_TOKENS][N_FEATURES]
    const signed char* __restrict__ qtab,     // [N_ROWS][EMB_DIM]
    const float*       __restrict__ scales,   // [N_ROWS]
    float*             __restrict__ out)      // [N_TOKENS][EMB_DIM]
{
    __shared__ int   sidx[8 * N_FEATURES];    // 8 tokens x 8 features
    __shared__ float sscl[8 * N_FEATURES];

    const int tid     = threadIdx.x;
    const int tok_blk = blockIdx.x * 8;

    if (tid < 16) {
        const v4i iv = __builtin_nontemporal_load(
            reinterpret_cast<const v4i*>(indices + (size_t)tok_blk * N_FEATURES) + tid);
        reinterpret_cast<v4i*>(sidx)[tid] = iv;
    }
    __syncthreads();
    if (tid < 64) {                           // one scattered vmem instr
        const int f = tid & 7;
        sscl[tid] = scales[f * VOCAB + sidx[tid]];
    }
    __syncthreads();

    const int tl  = tid >> 5;                 // token within block
    const int q   = tid & 31;                 // 8-dim chunk
    const int tok = tok_blk + tl;
    const int* myidx = sidx + tl * N_FEATURES;

    uint2 u[N_FEATURES];
#pragma unroll
    for (int f = 0; f < N_FEATURES; ++f) {
        const int row = f * VOCAB + myidx[f];
        u[f] = *reinterpret_cast<const uint2*>(qtab + (size_t)row * EMB_DIM + q * 8);
    }

    float acc[8] = {0.f, 0.f, 0.f, 0.f, 0.f, 0.f, 0.f, 0.f};
#pragma unroll
    for (int f = 0; f < N_FEATURES; ++f) {
        const float s = sscl[tl * N_FEATURES + f];   // LDS broadcast
        acc[0] += s * (float)(signed char)(u[f].x);
        acc[1] += s * (float)(signed char)(u[f].x >> 8);
        acc[2] += s * (float)(signed char)(u[f].x >> 16);
        acc[3] += s * (float)(signed char)(u[f].x >> 24);
        acc[4] += s * (float)(signed char)(u[f].y);
        acc[5] += s * (float)(signed char)(u[f].y >> 8);
        acc[6] += s * (float)(signed char)(u[f].y >> 16);
        acc[7] += s * (float)(signed char)(u[f].y >> 24);
    }

    const v4f lo = { acc[0], acc[1], acc[2], acc[3] };
    const v4f hi = { acc[4], acc[5], acc[6], acc[7] };
    float* p = out + (size_t)tok * EMB_DIM + q * 8;
    // full cache bypass: do not allocate in L1/L2 (protect the table)
    asm volatile(
        "global_store_dwordx4 %0, %1, off sc0 sc1 nt\n\t"
        "global_store_dwordx4 %0, %2, off offset:16 sc0 sc1 nt"
        :: "v"(p), "v"(lo), "v"(hi) : "memory");
}

// ---------- fallback: fp32 gather (if ws too small) ----------
__global__ __launch_bounds__(256) void emb_gather_sum_f32(
    const int*   __restrict__ indices,
    const float* __restrict__ tables,
    float*       __restrict__ out)
{
    const int gid = blockIdx.x * blockDim.x + threadIdx.x;
    const int t   = gid >> 6;
    const int c   = (gid & 63) << 2;

    const int* __restrict__ idx = indices + t * N_FEATURES;
    float4 acc = make_float4(0.f, 0.f, 0.f, 0.f);
#pragma unroll
    for (int f = 0; f < N_FEATURES; ++f) {
        const int ixv = idx[f];
        const float4 v = *reinterpret_cast<const float4*>(
            tables + ((size_t)f * VOCAB + (size_t)ixv) * EMB_DIM + c);
        acc.x += v.x; acc.y += v.y; acc.z += v.z; acc.w += v.w;
    }
    *reinterpret_cast<float4*>(out + (size_t)t * EMB_DIM + c) = acc;
}

extern "C" void kernel_launch(void* const* d_in, const int* in_sizes, int n_in,
                              void* d_out, int out_size, void* d_ws, size_t ws_size,
                              hipStream_t stream) {
    const int*   indices = (const int*)d_in[0];
    const float* tables  = (const float*)d_in[1];
    float*       out     = (float*)d_out;

    if (ws_size >= WS_NEED) {
        signed char* qtab   = (signed char*)d_ws;
        float*       scales = (float*)((char*)d_ws + SCALE_OFF);

        quant_table_i8<<<N_ROWS / 4, 256, 0, stream>>>(tables, qtab, scales);

        emb_gather_sum_i8hc<<<N_TOKENS / 8, 256, 0, stream>>>(
            indices, qtab, scales, out);
    } else {
        const int total_threads = N_TOKENS * 64;
        emb_gather_sum_f32<<<total_threads / 256, 256, 0, stream>>>(
            indices, tables, out);
    }
}

// Round 11
// 31.807 us; speedup vs baseline: 2.2688x; 2.2688x over previous
//
#include <hip/hip_runtime.h>

constexpr int N_TOKENS    = 65536;
constexpr int N_FEATURES  = 8;
constexpr int VOCAB       = 1026;
constexpr int EMB_DIM     = 256;
constexpr int N_ROWS      = N_FEATURES * VOCAB;          // 8208
constexpr int TABLE_ELEMS = N_ROWS * EMB_DIM;            // 2,101,248

constexpr size_t SCALE_OFF = (size_t)TABLE_ELEMS;
constexpr size_t WS_NEED   = SCALE_OFF + (size_t)N_ROWS * sizeof(float);

using v4f = __attribute__((ext_vector_type(4))) float;
using v4i = __attribute__((ext_vector_type(4))) int;

// ---------- prep: fp32 table -> per-row symmetric int8 (unchanged) ----------
__global__ __launch_bounds__(256) void quant_table_i8(
    const float* __restrict__ src,
    signed char* __restrict__ qtab,
    float*       __restrict__ scales)
{
    const int wid  = (blockIdx.x * 256 + threadIdx.x) >> 6;   // row
    const int lane = threadIdx.x & 63;

    const v4f v = __builtin_nontemporal_load(
        reinterpret_cast<const v4f*>(src + (size_t)wid * EMB_DIM) + lane);

    float m = fmaxf(fmaxf(fabsf(v.x), fabsf(v.y)), fmaxf(fabsf(v.z), fabsf(v.w)));
#pragma unroll
    for (int off = 32; off >= 1; off >>= 1)
        m = fmaxf(m, __shfl_xor(m, off));

    const float r = (m > 0.f) ? (127.0f / m) : 0.f;
    const int qx = (int)rintf(v.x * r);
    const int qy = (int)rintf(v.y * r);
    const int qz = (int)rintf(v.z * r);
    const int qw = (int)rintf(v.w * r);
    const unsigned int packed = (qx & 255) | ((qy & 255) << 8) |
                                ((qz & 255) << 16) | ((unsigned)(qw & 255) << 24);
    *reinterpret_cast<unsigned int*>(qtab + (size_t)wid * EMB_DIM + lane * 4) = packed;

    if (lane == 0) scales[wid] = m * (1.0f / 127.0f);
}

// ---------- main: R9 structure, PLAIN write-back stores ----------
// Only change vs R9: output stores are normal (no nt). R10's counters proved
// nt/bypass stores reach HBM as 2x-inflated partial-line bursts (~2 TB/s);
// write-back lets L2 merge the 16B half-line pairs into full 64B evictions.
__global__ __launch_bounds__(256) void emb_gather_sum_i8ilp(
    const int*         __restrict__ indices,  // [N_TOKENS][N_FEATURES]
    const signed char* __restrict__ qtab,     // [N_ROWS][EMB_DIM]
    const float*       __restrict__ scales,   // [N_ROWS]
    float*             __restrict__ out)      // [N_TOKENS][EMB_DIM]
{
    __shared__ int   sidx[16 * N_FEATURES];   // 16 tokens x 8
    __shared__ float sscl[16 * N_FEATURES];

    const int tid     = threadIdx.x;
    const int tok_blk = blockIdx.x * 16;

    if (tid < 32) {
        const v4i iv = __builtin_nontemporal_load(
            reinterpret_cast<const v4i*>(indices + (size_t)tok_blk * N_FEATURES) + tid);
        reinterpret_cast<v4i*>(sidx)[tid] = iv;
    }
    __syncthreads();
    if (tid < 128) {                          // one scattered vmem instr (2 waves)
        const int f = tid & 7;
        sscl[tid] = scales[f * VOCAB + sidx[tid]];
    }
    __syncthreads();

    const int q  = tid & 31;                  // 8-dim chunk within row
    const int tp = tid >> 5;                  // token pair 0..7
    const int t0 = tp * 2;                    // local token of pair

    // issue all 16 gathers (independent, deep in flight)
    uint2 u[2][N_FEATURES];
#pragma unroll
    for (int k = 0; k < 2; ++k) {
#pragma unroll
        for (int f = 0; f < N_FEATURES; ++f) {
            const int row = f * VOCAB + sidx[(t0 + k) * N_FEATURES + f];
            u[k][f] = *reinterpret_cast<const uint2*>(
                qtab + (size_t)row * EMB_DIM + q * 8);
        }
    }

#pragma unroll
    for (int k = 0; k < 2; ++k) {
        float acc[8] = {0.f, 0.f, 0.f, 0.f, 0.f, 0.f, 0.f, 0.f};
#pragma unroll
        for (int f = 0; f < N_FEATURES; ++f) {
            const float s = sscl[(t0 + k) * N_FEATURES + f];   // LDS broadcast
            acc[0] += s * (float)(signed char)(u[k][f].x);
            acc[1] += s * (float)(signed char)(u[k][f].x >> 8);
            acc[2] += s * (float)(signed char)(u[k][f].x >> 16);
            acc[3] += s * (float)(signed char)(u[k][f].x >> 24);
            acc[4] += s * (float)(signed char)(u[k][f].y);
            acc[5] += s * (float)(signed char)(u[k][f].y >> 8);
            acc[6] += s * (float)(signed char)(u[k][f].y >> 16);
            acc[7] += s * (float)(signed char)(u[k][f].y >> 24);
        }
        const v4f lo = { acc[0], acc[1], acc[2], acc[3] };
        const v4f hi = { acc[4], acc[5], acc[6], acc[7] };
        v4f* dst = reinterpret_cast<v4f*>(
            out + (size_t)(tok_blk + t0 + k) * EMB_DIM + q * 8);
        dst[0] = lo;                          // plain write-back stores
        dst[1] = hi;
    }
}

// ---------- fallback: fp32 gather (if ws too small) ----------
__global__ __launch_bounds__(256) void emb_gather_sum_f32(
    const int*   __restrict__ indices,
    const float* __restrict__ tables,
    float*       __restrict__ out)
{
    const int gid = blockIdx.x * blockDim.x + threadIdx.x;
    const int t   = gid >> 6;
    const int c   = (gid & 63) << 2;

    const int* __restrict__ idx = indices + t * N_FEATURES;
    float4 acc = make_float4(0.f, 0.f, 0.f, 0.f);
#pragma unroll
    for (int f = 0; f < N_FEATURES; ++f) {
        const int ixv = idx[f];
        const float4 v = *reinterpret_cast<const float4*>(
            tables + ((size_t)f * VOCAB + (size_t)ixv) * EMB_DIM + c);
        acc.x += v.x; acc.y += v.y; acc.z += v.z; acc.w += v.w;
    }
    *reinterpret_cast<float4*>(out + (size_t)t * EMB_DIM + c) = acc;
}

extern "C" void kernel_launch(void* const* d_in, const int* in_sizes, int n_in,
                              void* d_out, int out_size, void* d_ws, size_t ws_size,
                              hipStream_t stream) {
    const int*   indices = (const int*)d_in[0];
    const float* tables  = (const float*)d_in[1];
    float*       out     = (float*)d_out;

    if (ws_size >= WS_NEED) {
        signed char* qtab   = (signed char*)d_ws;
        float*       scales = (float*)((char*)d_ws + SCALE_OFF);

        quant_table_i8<<<N_ROWS / 4, 256, 0, stream>>>(tables, qtab, scales);

        emb_gather_sum_i8ilp<<<N_TOKENS / 16, 256, 0, stream>>>(
            indices, qtab, scales, out);
    } else {
        const int total_threads = N_TOKENS * 64;
        emb_gather_sum_f32<<<total_threads / 256, 256, 0, stream>>>(
            indices, tables, out);
    }
}

// Round 12
// 26.243 us; speedup vs baseline: 2.7497x; 1.2120x over previous
//
#include <hip/hip_runtime.h>

constexpr int N_TOKENS    = 65536;
constexpr int N_FEATURES  = 8;
constexpr int VOCAB       = 1026;
constexpr int EMB_DIM     = 256;
constexpr int N_ROWS      = N_FEATURES * VOCAB;          // 8208
constexpr int TABLE_ELEMS = N_ROWS * EMB_DIM;            // 2,101,248

constexpr size_t SCALE_OFF = (size_t)TABLE_ELEMS;
constexpr size_t WS_NEED   = SCALE_OFF + (size_t)N_ROWS * sizeof(float);

using v4f = __attribute__((ext_vector_type(4))) float;
using v4i = __attribute__((ext_vector_type(4))) int;

// ---------- prep: fp32 table -> per-row symmetric int8 (unchanged) ----------
__global__ __launch_bounds__(256) void quant_table_i8(
    const float* __restrict__ src,
    signed char* __restrict__ qtab,
    float*       __restrict__ scales)
{
    const int wid  = (blockIdx.x * 256 + threadIdx.x) >> 6;   // row
    const int lane = threadIdx.x & 63;

    const v4f v = __builtin_nontemporal_load(
        reinterpret_cast<const v4f*>(src + (size_t)wid * EMB_DIM) + lane);

    float m = fmaxf(fmaxf(fabsf(v.x), fabsf(v.y)), fmaxf(fabsf(v.z), fabsf(v.w)));
#pragma unroll
    for (int off = 32; off >= 1; off >>= 1)
        m = fmaxf(m, __shfl_xor(m, off));

    const float r = (m > 0.f) ? (127.0f / m) : 0.f;
    const int qx = (int)rintf(v.x * r);
    const int qy = (int)rintf(v.y * r);
    const int qz = (int)rintf(v.z * r);
    const int qw = (int)rintf(v.w * r);
    const unsigned int packed = (qx & 255) | ((qy & 255) << 8) |
                                ((qz & 255) << 16) | ((unsigned)(qw & 255) << 24);
    *reinterpret_cast<unsigned int*>(qtab + (size_t)wid * EMB_DIM + lane * 4) = packed;

    if (lane == 0) scales[wid] = m * (1.0f / 127.0f);
}

// ---------- main: R9 ILP gather + LDS transpose + TRUE-bypass full-line stores ----------
// Theory: the 64 MiB output stream, when it allocates in L2, sweeps the 4 MiB
// per-XCD L2 and evicts the 2.1 MB table -> gathers are L3-latency/MSHR-bound
// (~25 us invariant). Fix: stores bypass ALL caches (sc0 sc1 nt) so the table
// stays L2-resident; the LDS transpose makes each store instruction 1 KiB
// contiguous so the bypass write reaches HBM as full 64 B lines (R10's 2x
// inflation came from 16B-stride-32B geometry, not bypass itself).
__global__ __launch_bounds__(256) void emb_gather_sum_i8t(
    const int*         __restrict__ indices,  // [N_TOKENS][N_FEATURES]
    const signed char* __restrict__ qtab,     // [N_ROWS][EMB_DIM]
    const float*       __restrict__ scales,   // [N_ROWS]
    float*             __restrict__ out)      // [N_TOKENS][EMB_DIM]
{
    __shared__ int   sidx[16 * N_FEATURES];   // 16 tokens x 8
    __shared__ float sscl[16 * N_FEATURES];
    __shared__ float sout[16 * EMB_DIM];      // 16 KB transpose buffer

    const int tid     = threadIdx.x;
    const int tok_blk = blockIdx.x * 16;

    if (tid < 32) {
        reinterpret_cast<v4i*>(sidx)[tid] =
            *(reinterpret_cast<const v4i*>(indices + (size_t)tok_blk * N_FEATURES) + tid);
    }
    __syncthreads();
    if (tid < 128) {                          // one scattered vmem instr (2 waves)
        const int f = tid & 7;
        sscl[tid] = scales[f * VOCAB + sidx[tid]];
    }
    __syncthreads();

    const int q  = tid & 31;                  // 8-dim chunk within row
    const int tp = tid >> 5;                  // token pair 0..7
    const int t0 = tp * 2;

    // issue all 16 gathers (independent, deep in flight)
    uint2 u[2][N_FEATURES];
#pragma unroll
    for (int k = 0; k < 2; ++k) {
#pragma unroll
        for (int f = 0; f < N_FEATURES; ++f) {
            const int row = f * VOCAB + sidx[(t0 + k) * N_FEATURES + f];
            u[k][f] = *reinterpret_cast<const uint2*>(
                qtab + (size_t)row * EMB_DIM + q * 8);
        }
    }

#pragma unroll
    for (int k = 0; k < 2; ++k) {
        float acc[8] = {0.f, 0.f, 0.f, 0.f, 0.f, 0.f, 0.f, 0.f};
#pragma unroll
        for (int f = 0; f < N_FEATURES; ++f) {
            const float s = sscl[(t0 + k) * N_FEATURES + f];   // LDS broadcast
            acc[0] += s * (float)(signed char)(u[k][f].x);
            acc[1] += s * (float)(signed char)(u[k][f].x >> 8);
            acc[2] += s * (float)(signed char)(u[k][f].x >> 16);
            acc[3] += s * (float)(signed char)(u[k][f].x >> 24);
            acc[4] += s * (float)(signed char)(u[k][f].y);
            acc[5] += s * (float)(signed char)(u[k][f].y >> 8);
            acc[6] += s * (float)(signed char)(u[k][f].y >> 16);
            acc[7] += s * (float)(signed char)(u[k][f].y >> 24);
        }
        // dim-ordered row in LDS: col 2q = dims[8q..8q+4), 2q+1 = next 4
        v4f* row = reinterpret_cast<v4f*>(sout + (size_t)(t0 + k) * EMB_DIM);
        const v4f lo = { acc[0], acc[1], acc[2], acc[3] };
        const v4f hi = { acc[4], acc[5], acc[6], acc[7] };
        row[2 * q]     = lo;
        row[2 * q + 1] = hi;
    }
    __syncthreads();

    // readback + store: block's 16 KB is contiguous in out; each wave store
    // instruction covers 64 lanes x 16 B = 1 KiB contiguous (full lines).
    const v4f* s4 = reinterpret_cast<const v4f*>(sout);
    float* ob = out + (size_t)tok_blk * EMB_DIM;
#pragma unroll
    for (int j = 0; j < 4; ++j) {
        const v4f w = s4[tid + j * 256];
        float* p = ob + (size_t)(tid + j * 256) * 4;
        asm volatile("global_store_dwordx4 %0, %1, off sc0 sc1 nt"
                     :: "v"(p), "v"(w) : "memory");
    }
}

// ---------- fallback: fp32 gather (if ws too small) ----------
__global__ __launch_bounds__(256) void emb_gather_sum_f32(
    const int*   __restrict__ indices,
    const float* __restrict__ tables,
    float*       __restrict__ out)
{
    const int gid = blockIdx.x * blockDim.x + threadIdx.x;
    const int t   = gid >> 6;
    const int c   = (gid & 63) << 2;

    const int* __restrict__ idx = indices + t * N_FEATURES;
    float4 acc = make_float4(0.f, 0.f, 0.f, 0.f);
#pragma unroll
    for (int f = 0; f < N_FEATURES; ++f) {
        const int ixv = idx[f];
        const float4 v = *reinterpret_cast<const float4*>(
            tables + ((size_t)f * VOCAB + (size_t)ixv) * EMB_DIM + c);
        acc.x += v.x; acc.y += v.y; acc.z += v.z; acc.w += v.w;
    }
    *reinterpret_cast<float4*>(out + (size_t)t * EMB_DIM + c) = acc;
}

extern "C" void kernel_launch(void* const* d_in, const int* in_sizes, int n_in,
                              void* d_out, int out_size, void* d_ws, size_t ws_size,
                              hipStream_t stream) {
    const int*   indices = (const int*)d_in[0];
    const float* tables  = (const float*)d_in[1];
    float*       out     = (float*)d_out;

    if (ws_size >= WS_NEED) {
        signed char* qtab   = (signed char*)d_ws;
        float*       scales = (float*)((char*)d_ws + SCALE_OFF);

        quant_table_i8<<<N_ROWS / 4, 256, 0, stream>>>(tables, qtab, scales);

        emb_gather_sum_i8t<<<N_TOKENS / 16, 256, 0, stream>>>(
            indices, qtab, scales, out);
    } else {
        const int total_threads = N_TOKENS * 64;
        emb_gather_sum_f32<<<total_threads / 256, 256, 0, stream>>>(
            indices, tables, out);
    }
}